// Round 9
// baseline (901.833 us; speedup 1.0000x reference)
//
#include <hip/hip_runtime.h>
#include <hip/hip_bf16.h>
#include <cstdint>

#define BB 32
#define NN 2048
#define EE 4096
#define HH 4
#define CC 64
#define DD 256            // H*C == D_IN
#define MM (BB*NN)        // 65536 rows
#define NB 1024           // fused grid: exact chip capacity (256 CU x 4 blocks)

typedef __attribute__((ext_vector_type(8))) short bf16x8;
typedef __attribute__((ext_vector_type(8))) unsigned short u16x8;
typedef __attribute__((ext_vector_type(4))) float f32x4;

__device__ __forceinline__ float b2f(__hip_bfloat16 x){ return __bfloat162float(x); }
__device__ __forceinline__ float u2f(unsigned short u){ return __uint_as_float((unsigned)u << 16); }
__device__ __forceinline__ unsigned short f2u(float f){
  __hip_bfloat16 h = __float2bfloat16(f);
  return *(unsigned short*)&h;
}
__device__ __forceinline__ float ldany(const void* p, int isf, size_t i){
  return isf ? ((const float*)p)[i] : b2f(((const __hip_bfloat16*)p)[i]);
}
__device__ __forceinline__ void gld_lds16(const void* g, void* l){
  __builtin_amdgcn_global_load_lds((const __attribute__((address_space(1))) uint32_t*)g,
                                   (__attribute__((address_space(3))) uint32_t*)l, 16, 0, 0);
}

// ---- grid-wide barrier: all NB blocks co-resident (capacity launch), one-shot
// counter zeroed by prep2 each iteration. Release fence + arrive + acquire spin.
__device__ __forceinline__ void grid_sync(int* cnt){
  __syncthreads();
  if(threadIdx.x == 0){
    __threadfence();                               // release (agent scope)
    atomicAdd(cnt, 1);
    while(__hip_atomic_load(cnt, __ATOMIC_ACQUIRE, __HIP_MEMORY_SCOPE_AGENT) < NB)
      __builtin_amdgcn_s_sleep(4);
  }
  __syncthreads();
}

// ---------------- dtype detection (unchanged — works) ----------------
__global__ void detect_kernel(const unsigned* __restrict__ w, int* __restrict__ flag){
  __shared__ int cnt;
  if(threadIdx.x == 0) cnt = 0;
  __syncthreads();
  int c = 0;
  #pragma unroll
  for(int i = 0; i < 4; ++i){
    unsigned v = w[threadIdx.x*4 + i];
    unsigned elo = (v >> 7) & 0xFFu;
    if(elo >= 100u && elo <= 150u) ++c;
  }
  atomicAdd(&cnt, c);
  __syncthreads();
  if(threadIdx.x == 0) *flag = (cnt < 128) ? 1 : 0;
}

// ---------------- merged prep: W1^T, W2^T, att/bias, CSR build, barrier reset ----------------
// blocks [0,256): W1t ; [256,512): W2t ; [512,518): att/bias ;
// [518,550): per-graph CSR (histogram+scan+scatter in LDS) ; 550: zero barrier counters.
__global__ __launch_bounds__(256) void prep2_kernel(const void* __restrict__ W1,
    const void* __restrict__ W2, __hip_bfloat16* __restrict__ W1t,
    __hip_bfloat16* __restrict__ W2t,
    const void* s0, const void* s1, const void* s2, const void* s3,
    const void* s4, const void* s5, float* __restrict__ attf,
    const int* __restrict__ srcI, const int* __restrict__ dstI,
    int* __restrict__ rowp, unsigned short* __restrict__ srcL,
    int* __restrict__ bar, const int* __restrict__ flag)
{
  __shared__ int ldeg[NN];                    // 8 KB: histogram, then cursors
  __shared__ int part[256];
  int bid = blockIdx.x, t = threadIdx.x;
  if(bid < 512){
    int isf = *flag;
    const void* W = (bid < 256) ? W1 : W2;
    __hip_bfloat16* WT = (bid < 256) ? W1t : W2t;
    int i = (bid & 255)*256 + t;              // [0, 65536)
    WT[i] = __float2bfloat16(ldany(W, isf, (size_t)(i & 255)*256 + (i >> 8)));
  } else if(bid < 518){
    int isf = *flag;
    int i = (bid - 512)*256 + t;              // [0, 1536)
    int seg = i >> 8, off = i & 255;
    const void* s = seg==0?s0 : seg==1?s1 : seg==2?s2 : seg==3?s3 : seg==4?s4 : s5;
    attf[i] = ldany(s, isf, off);
  } else if(bid < 550){
    // ---- CSR for graph g, fully block-local ----
    int g = bid - 518;                        // [0, 32)
    const int* ds = dstI + g*EE;
    const int* ss = srcI + g*EE;
    for(int i = t; i < NN; i += 256) ldeg[i] = 0;
    __syncthreads();
    for(int i = t; i < EE; i += 256) atomicAdd(&ldeg[ds[i] & (NN-1)], 1);
    __syncthreads();
    int loc[8], s = 0;
    #pragma unroll
    for(int k = 0; k < 8; ++k){ loc[k] = s; s += ldeg[t*8 + k]; }
    part[t] = s;
    __syncthreads();
    if(t == 0){
      int run = 0;
      for(int i = 0; i < 256; ++i){ int tmp = part[i]; part[i] = run; run += tmp; }
    }
    __syncthreads();
    int base = g*EE + part[t];
    int cur[8];
    #pragma unroll
    for(int k = 0; k < 8; ++k){
      int v = base + loc[k];
      rowp[g*(NN+1) + t*8 + k] = v;
      cur[k] = v;
    }
    if(t == 255) rowp[g*(NN+1) + NN] = base + s;
    __syncthreads();                          // scan reads of ldeg complete
    #pragma unroll
    for(int k = 0; k < 8; ++k) ldeg[t*8 + k] = cur[k];
    __syncthreads();                          // cursors published
    for(int i = t; i < EE; i += 256){
      int pos = atomicAdd(&ldeg[ds[i] & (NN-1)], 1);
      srcL[pos] = (unsigned short)ss[i];
    }
  } else {
    if(t < 48) bar[t] = 0;                    // one-shot grid-barrier counters
  }
}

// ---------------- GEMM tile phase (r2 champion, as device function) ----------------
// XCD-affine flat id dd: XCD k owns row-blocks [64k,64k+64); both col-blocks of a
// row-block on the same XCD. DYNA=1: A may be fp32 (reg-stage + convert into LDS).
template<int DYNA>
__device__ __forceinline__ void gemm_tile(const void* __restrict__ Ap,
    const __hip_bfloat16* __restrict__ BT, __hip_bfloat16* __restrict__ C,
    const float* __restrict__ attS, const float* __restrict__ attD,
    float* __restrict__ aS, float* __restrict__ aD, const int* __restrict__ flag,
    short* lds)
{
  short* lA = lds;
  short* lB = lds + 128*64;
  const int isf  = DYNA ? *flag : 0;
  const int tid  = threadIdx.x;
  const int w    = tid >> 6, lane = tid & 63;
  const int dd   = blockIdx.x;                     // 0..1023
  const int xcd  = dd & 7, slot = dd >> 3;         // 128 slots per XCD
  const int rb   = xcd*64 + (slot >> 1), cb = slot & 1;
  const int row0 = rb*128, col0 = cb*128;
  const int wr   = (w & 1)*64, wc = (w >> 1)*64;
  const int lr   = lane >> 3;
  const int kb_g = (lane & 7) ^ lr;
  const int fm   = lane & 15, quad = lane >> 4;
  f32x4 acc[4][4] = {};

  for(int k0 = 0; k0 < 256; k0 += 64){
    #pragma unroll
    for(int c = 0; c < 4; ++c){
      int ra = w*32 + c*8;
      const short* gb = (const short*)BT + (size_t)(col0 + ra + lr)*DD + k0 + kb_g*8;
      gld_lds16(gb, &lB[ra*64]);
    }
    if(DYNA && isf){
      const float* Af = (const float*)Ap;
      float4 ta[4], tb[4];
      #pragma unroll
      for(int i = 0; i < 4; ++i){
        int f8 = i*256 + tid;                  // [0,1024): (row m, k-block kb)
        int m = f8 >> 3, kb = f8 & 7;
        const float* p = Af + (size_t)(row0 + m)*DD + k0 + kb*8;
        ta[i] = *(const float4*)p;
        tb[i] = *(const float4*)(p + 4);
      }
      #pragma unroll
      for(int i = 0; i < 4; ++i){
        int f8 = i*256 + tid;
        int m = f8 >> 3, kb = f8 & 7;
        u16x8 o;
        o[0] = f2u(ta[i].x); o[1] = f2u(ta[i].y); o[2] = f2u(ta[i].z); o[3] = f2u(ta[i].w);
        o[4] = f2u(tb[i].x); o[5] = f2u(tb[i].y); o[6] = f2u(tb[i].z); o[7] = f2u(tb[i].w);
        *(u16x8*)&lA[m*64 + ((kb ^ (m & 7))*8)] = o;
      }
    } else {
      #pragma unroll
      for(int c = 0; c < 4; ++c){
        int ra = w*32 + c*8;
        const short* ga = (const short*)Ap + (size_t)(row0 + ra + lr)*DD + k0 + kb_g*8;
        gld_lds16(ga, &lA[ra*64]);
      }
    }
    __syncthreads();
    #pragma unroll
    for(int ks = 0; ks < 2; ++ks){
      bf16x8 af[4], bfr[4];
      int kb = ks*4 + quad;
      #pragma unroll
      for(int i = 0; i < 4; ++i){
        int m = wr + i*16 + fm;
        af[i]  = *(const bf16x8*)&lA[m*64 + ((kb ^ (m & 7))*8)];
        int n = wc + i*16 + fm;
        bfr[i] = *(const bf16x8*)&lB[n*64 + ((kb ^ (n & 7))*8)];
      }
      #pragma unroll
      for(int i = 0; i < 4; ++i)
        #pragma unroll
        for(int j = 0; j < 4; ++j)
          acc[i][j] = __builtin_amdgcn_mfma_f32_16x16x32_bf16(af[i], bfr[j], acc[i][j], 0, 0, 0);
    }
    __syncthreads();
  }

  // ---- fused attention logits ----
  const int headI = (col0 + wc) >> 6;
  float ws_[4], wd_[4];
  #pragma unroll
  for(int j = 0; j < 4; ++j){
    ws_[j] = attS[headI*CC + j*16 + fm];
    wd_[j] = attD[headI*CC + j*16 + fm];
  }
  #pragma unroll
  for(int i = 0; i < 4; ++i){
    #pragma unroll
    for(int r = 0; r < 4; ++r){
      float s = 0.f, dv = 0.f;
      #pragma unroll
      for(int j = 0; j < 4; ++j){
        float v = acc[i][j][r];
        s  += v * ws_[j];
        dv += v * wd_[j];
      }
      #pragma unroll
      for(int m = 1; m <= 8; m <<= 1){
        s  += __shfl_xor(s,  m);
        dv += __shfl_xor(dv, m);
      }
      if(fm == i*4 + r){
        int row = row0 + wr + i*16 + quad*4 + r;
        aS[(size_t)row*HH + headI] = s;
        aD[(size_t)row*HH + headI] = dv;
      }
    }
  }

  // ---- C store via LDS transpose ----
  #pragma unroll
  for(int i = 0; i < 4; ++i)
    #pragma unroll
    for(int j = 0; j < 4; ++j)
      #pragma unroll
      for(int r = 0; r < 4; ++r){
        int rl = wr + i*16 + quad*4 + r;
        int cl = wc + j*16 + fm;
        lds[rl*128 + (cl ^ ((rl & 12) << 2))] = (short)f2u(acc[i][j][r]);
      }
  __syncthreads();
  const int rr = tid >> 4, cc = (tid & 15)*8;
  #pragma unroll
  for(int p = 0; p < 8; ++p){
    int rl = p*16 + rr;
    u16x8 v = *(const u16x8*)&lds[rl*128 + (cc ^ ((rl & 12) << 2))];
    *(u16x8*)((unsigned short*)C + (size_t)(row0 + rl)*DD + col0 + cc) = v;
  }
  __syncthreads();                                 // lds reuse safe for next phase
}

// ---------------- gather phase: 64 nodes per block, one wave per node-iteration ----------------
// XCD-affine: block's nodes lie in the SAME XCD row-range its GEMM tile wrote.
template<int LAYER>
__device__ __forceinline__ void gather_phase(const __hip_bfloat16* __restrict__ H,
    const float* __restrict__ a_src, const float* __restrict__ a_dst,
    const int* __restrict__ row_ptr, const unsigned short* __restrict__ srcList,
    const float* __restrict__ bias, void* __restrict__ outp,
    const int* __restrict__ flag)
{
  const int dd   = blockIdx.x;
  const int w    = threadIdx.x >> 6, lane = threadIdx.x & 63;
  const int base = (dd & 7)*8192 + (dd >> 3)*64;   // 64 nodes per block, XCD-affine
  const int head = lane >> 4;
  const unsigned short* Hu = (const unsigned short*)H;
  const float4 bs = *(const float4*)(bias + lane*4);
  const int isf = (LAYER == 2) ? *flag : 0;

  for(int it = 0; it < 16; ++it){
    int wid = base + it*4 + w;                     // b*NN + d
    int b = wid >> 11, d = wid & (NN-1);
    int start = row_ptr[b*(NN+1) + d];
    int end   = row_ptr[b*(NN+1) + d + 1];

    float adv = a_dst[wid*HH + head];
    float sv  = a_src[wid*HH + head] + adv;        // self-loop logit
    sv = sv > 0.f ? sv : 0.2f*sv;
    float exs = __expf(sv);

    ushort4 hv = *(const ushort4*)(Hu + (size_t)wid*DD + lane*4);
    f32x4 acc;
    acc.x = exs*u2f(hv.x); acc.y = exs*u2f(hv.y); acc.z = exs*u2f(hv.z); acc.w = exs*u2f(hv.w);
    float den = exs;

    int e = start;
    float ax = 0.f; ushort4 hw = {0,0,0,0};
    if(e < end){
      int s = srcList[e];
      ax = a_src[(b*NN + s)*HH + head];
      hw = *(const ushort4*)(Hu + (size_t)(b*NN + s)*DD + lane*4);
    }
    while(e < end){
      float axn = 0.f; ushort4 hwn = {0,0,0,0};
      if(e + 1 < end){
        int sn = srcList[e+1];
        axn = a_src[(b*NN + sn)*HH + head];
        hwn = *(const ushort4*)(Hu + (size_t)(b*NN + sn)*DD + lane*4);
      }
      float v = ax + adv;
      v = v > 0.f ? v : 0.2f*v;
      float ex = __expf(v);
      acc.x += ex*u2f(hw.x); acc.y += ex*u2f(hw.y); acc.z += ex*u2f(hw.z); acc.w += ex*u2f(hw.w);
      den += ex;
      ax = axn; hw = hwn; ++e;
    }
    float inv = 1.f / (den + 1e-16f);
    float o0 = acc.x*inv + bs.x, o1 = acc.y*inv + bs.y;
    float o2 = acc.z*inv + bs.z, o3 = acc.w*inv + bs.w;
    size_t oi = (size_t)wid*DD + lane*4;
    if(LAYER == 1){
      o0 = o0 > 0.f ? o0 : expm1f(o0);
      o1 = o1 > 0.f ? o1 : expm1f(o1);
      o2 = o2 > 0.f ? o2 : expm1f(o2);
      o3 = o3 > 0.f ? o3 : expm1f(o3);
      ushort4 ov = { f2u(o0), f2u(o1), f2u(o2), f2u(o3) };
      *(ushort4*)((unsigned short*)outp + oi) = ov;
    } else {
      if(isf){
        float4 ov = { o0, o1, o2, o3 };
        *(float4*)((float*)outp + oi) = ov;
      } else {
        ushort4 ov = { f2u(o0), f2u(o1), f2u(o2), f2u(o3) };
        *(ushort4*)((unsigned short*)outp + oi) = ov;
      }
    }
  }
}

// ---------------- fused: gemm1 -> gather1 -> gemm2 -> gather2, 3 grid barriers ----------------
// Grid = 1024 = exact capacity at (256 threads, <=128 VGPR, 32 KB LDS) => all blocks
// co-resident; no conditional returns anywhere; barriers are deadlock-free.
__global__ __launch_bounds__(256, 4) void fused_kernel(const void* __restrict__ x_in,
    const __hip_bfloat16* __restrict__ W1t, const __hip_bfloat16* __restrict__ W2t,
    __hip_bfloat16* __restrict__ R1, __hip_bfloat16* __restrict__ R2,
    float* __restrict__ a_src, float* __restrict__ a_dst,
    const int* __restrict__ rowp, const unsigned short* __restrict__ srcL,
    const float* __restrict__ attf, void* __restrict__ outp,
    const int* __restrict__ flag, int* __restrict__ bar)
{
  __shared__ __align__(16) short lds[128*128];     // 32 KB

  gemm_tile<1>(x_in, W1t, R2, attf + 0, attf + 256, a_src, a_dst, flag, lds);
  grid_sync(bar + 0);
  gather_phase<1>(R2, a_src, a_dst, rowp, srcL, attf + 512, R1, flag);
  grid_sync(bar + 16);
  gemm_tile<0>(R1, W2t, R2, attf + 768, attf + 1024, a_src, a_dst, flag, lds);
  grid_sync(bar + 32);
  gather_phase<2>(R2, a_src, a_dst, rowp, srcL, attf + 1280, outp, flag);
}

extern "C" void kernel_launch(void* const* d_in, const int* in_sizes, int n_in,
                              void* d_out, int out_size, void* d_ws, size_t ws_size,
                              hipStream_t stream)
{
  const void* x_in = d_in[0];
  const int*  srcI = (const int*)d_in[1];
  const int*  dstI = (const int*)d_in[2];
  const void* W1   = d_in[3];
  const void* as1  = d_in[4];
  const void* ad1  = d_in[5];
  const void* b1   = d_in[6];
  const void* W2   = d_in[7];
  const void* as2  = d_in[8];
  const void* ad2  = d_in[9];
  const void* b2   = d_in[10];

  // Workspace (~66 MiB)
  char* ws = (char*)d_ws;
  __hip_bfloat16* R1  = (__hip_bfloat16*)ws; ws += (size_t)MM*DD*2;        // 32 MiB
  __hip_bfloat16* R2  = (__hip_bfloat16*)ws; ws += (size_t)MM*DD*2;        // 32 MiB
  float* a_src = (float*)ws; ws += (size_t)MM*HH*4;                        // 1 MiB
  float* a_dst = (float*)ws; ws += (size_t)MM*HH*4;                        // 1 MiB
  __hip_bfloat16* W1t = (__hip_bfloat16*)ws; ws += (size_t)DD*DD*2;        // 128 KiB
  __hip_bfloat16* W2t = (__hip_bfloat16*)ws; ws += (size_t)DD*DD*2;        // 128 KiB
  float* attf = (float*)ws; ws += 1536*4;
  int*   rowp = (int*)ws;   ws += (size_t)BB*(NN+1)*4;
  unsigned short* srcL = (unsigned short*)ws; ws += (size_t)BB*EE*2;
  int*   flag = (int*)ws;   ws += 16;
  int*   bar  = (int*)ws;   ws += 48*4;            // 3 counters, 64B apart

  // ---- 3 dispatches total ----
  detect_kernel<<<1, 64, 0, stream>>>((const unsigned*)x_in, flag);
  prep2_kernel<<<551, 256, 0, stream>>>(W1, W2, W1t, W2t,
                                        as1, ad1, b1, as2, ad2, b2, attf,
                                        srcI, dstI, rowp, srcL, bar, flag);
  fused_kernel<<<NB, 256, 0, stream>>>(x_in, W1t, W2t, R1, R2, a_src, a_dst,
                                       rowp, srcL, attf, d_out, flag, bar);
}